// Round 9
// baseline (246.540 us; speedup 1.0000x reference)
//
#include <hip/hip_runtime.h>
#include <math.h>
#include <stdint.h>

#define SEQ 4096
#define DMODEL 512
#define NH 4
#define DH 128

typedef short s16x8 __attribute__((ext_vector_type(8)));
typedef float f32x4 __attribute__((ext_vector_type(4)));

__device__ __forceinline__ ushort f2bf(float f) {
    uint32_t u = __builtin_bit_cast(uint32_t, f);
    u += 0x7FFFu + ((u >> 16) & 1u);
    return (ushort)(u >> 16);
}

__device__ __forceinline__ void gl2lds16(const void* g, void* l) {
    __builtin_amdgcn_global_load_lds(
        (const __attribute__((address_space(1))) uint32_t*)g,
        (__attribute__((address_space(3))) uint32_t*)l, 16, 0, 0);
}

// ---------------------------------------------------------------------------
// Cast fp32 -> bf16 (unchanged, validated).
// ---------------------------------------------------------------------------
__global__ __launch_bounds__(256) void cast_bf16(
    const float* __restrict__ src, ushort* __restrict__ dst)
{
    const size_t i = ((size_t)blockIdx.x * 256 + threadIdx.x) * 8;
    float4 f0 = *(const float4*)&src[i];
    float4 f1 = *(const float4*)&src[i + 4];
    s16x8 o;
    o[0] = (short)f2bf(f0.x); o[1] = (short)f2bf(f0.y);
    o[2] = (short)f2bf(f0.z); o[3] = (short)f2bf(f0.w);
    o[4] = (short)f2bf(f1.x); o[5] = (short)f2bf(f1.y);
    o[6] = (short)f2bf(f1.z); o[7] = (short)f2bf(f1.w);
    *(s16x8*)&dst[i] = o;
}

// ---------------------------------------------------------------------------
// Kernel A: QKV projection, bf16 MFMA (unchanged, validated rounds 7-8).
// ---------------------------------------------------------------------------
__global__ __launch_bounds__(256) void qkv_gemm(
    const ushort* __restrict__ xb, const ushort* __restrict__ Wb,
    const float* __restrict__ bias,
    ushort* __restrict__ Qb, ushort* __restrict__ Kb, ushort* __restrict__ Vt)
{
    __shared__ char As[16384];   // [row 0..127][8 chunks of 16B], chunk^(row&7)
    __shared__ char Bs[16384];

    const int t   = threadIdx.x;
    const int l   = t & 63;
    const int w   = t >> 6;
    const int l15 = l & 15;
    const int g   = l >> 4;
    const int n0  = blockIdx.x * 128;
    const int m0  = blockIdx.y * 128;
    const int wr  = w >> 1, wc = w & 1;

    f32x4 acc[4][4];
#pragma unroll
    for (int mi = 0; mi < 4; ++mi)
#pragma unroll
        for (int ni = 0; ni < 4; ++ni) acc[mi][ni] = (f32x4)(0.f);

    for (int step = 0; step < 8; ++step) {
        const int k0 = step * 64;
        __syncthreads();
#pragma unroll
        for (int it = 0; it < 4; ++it) {
            const int slot = it * 256 + t;
            const int r    = slot >> 3;
            const int cs   = slot & 7;
            const int c    = cs ^ (r & 7);
            char* lA = As + (size_t)(it * 256 + 64 * w) * 16;
            gl2lds16(xb + (size_t)(m0 + r) * DMODEL + k0 + c * 8, lA);
            char* lB = Bs + (size_t)(it * 256 + 64 * w) * 16;
            gl2lds16(Wb + (size_t)(n0 + r) * DMODEL + k0 + c * 8, lB);
        }
        __syncthreads();

#pragma unroll
        for (int ks = 0; ks < 2; ++ks) {
            s16x8 af[4], bf[4];
#pragma unroll
            for (int mi = 0; mi < 4; ++mi) {
                const int row = 64 * wr + 16 * mi + l15;
                const int ch  = (4 * ks + g) ^ (row & 7);
                af[mi] = *(const s16x8*)(As + row * 128 + ch * 16);
            }
#pragma unroll
            for (int ni = 0; ni < 4; ++ni) {
                const int row = 64 * wc + 16 * ni + l15;
                const int ch  = (4 * ks + g) ^ (row & 7);
                bf[ni] = *(const s16x8*)(Bs + row * 128 + ch * 16);
            }
#pragma unroll
            for (int mi = 0; mi < 4; ++mi)
#pragma unroll
                for (int ni = 0; ni < 4; ++ni)
                    acc[mi][ni] = __builtin_amdgcn_mfma_f32_16x16x32_bf16(
                        af[mi], bf[ni], acc[mi][ni], 0, 0, 0);
        }
    }

    const float scale = 0.08838834764831845f;  // 128^-0.5
#pragma unroll
    for (int ni = 0; ni < 4; ++ni) {
        const int o     = n0 + 64 * wc + 16 * ni + l15;
        const float bv  = bias[o];
        const int which = o >> 9;
        const int rem   = o & 511;
        const int d     = rem >> 2;
        const int h     = rem & 3;
#pragma unroll
        for (int mi = 0; mi < 4; ++mi)
#pragma unroll
            for (int i = 0; i < 4; ++i) {
                const int m    = m0 + 64 * wr + 16 * mi + 4 * g + i;
                const int bidx = m >> 12;
                const int npos = m & 4095;
                const int bhh  = bidx * NH + h;
                const float val = acc[mi][ni][i] + bv;
                if (which == 0)
                    Qb[((size_t)bhh * SEQ + npos) * DH + d] = f2bf(val * scale);
                else if (which == 1)
                    Kb[((size_t)bhh * SEQ + npos) * DH + d] = f2bf(val);
                else
                    Vt[((size_t)bhh * DH + d) * SEQ + npos] = f2bf(val);
            }
    }
}

// ---------------------------------------------------------------------------
// Kernel B: flash attention, split-K partials.
// ROUND 9 CHANGE: 8 waves x 32 q-rows (BQ=256) so each K/V fragment read
// feeds 2 MFMAs (halves LDS bytes/FLOP — R8 was LDS-read bound at 26%
// MfmaUtil). Grid (16,16): x = bh*2+split (same-(bh,split) q-blocks share an
// XCD), y = q-tile. Each block does 16 k-tiles (2048 keys), writes
// UNNORMALIZED partial O + partial row-sum l (static-max softmax => combine
// is just (O0+O1)/(l0+l1)). Per-wave body = validated round-2 structure.
// LDS 128KB: Ks[128x128] | Vs[128x128 of V^T] | Ps 8 waves x [32][128] bf16.
// ---------------------------------------------------------------------------
__global__ __launch_bounds__(512) void flash_attn_mfma(
    const ushort* __restrict__ Qb, const ushort* __restrict__ Kb,
    const ushort* __restrict__ Vt,
    float* __restrict__ Opart, float* __restrict__ lpart)
{
    extern __shared__ char smem[];
    char* KsB = smem;            // 32 KiB
    char* VsB = smem + 32768;    // 32 KiB
    char* PsB = smem + 65536;    // 64 KiB (8 KiB per wave)

    const int t     = threadIdx.x;
    const int l     = t & 63;
    const int w     = t >> 6;    // wave 0..7, owns q-rows [32w, 32w+32)
    const int l15   = l & 15;
    const int g     = l >> 4;
    const int xs    = blockIdx.x;     // bh*2 + split
    const int bh    = xs >> 1;
    const int split = xs & 1;
    const int q0    = blockIdx.y * 256;

    // Q fragments: A[row=l15][k=32ks+8g+j], rows 16m+l15 of wave's 32
    s16x8 qf[2][4];
    {
        const ushort* qbase = Qb + ((size_t)bh * SEQ + q0 + 32 * w) * DH;
#pragma unroll
        for (int m = 0; m < 2; ++m)
#pragma unroll
            for (int ks = 0; ks < 4; ++ks)
                qf[m][ks] = *(const s16x8*)&qbase[(size_t)(16 * m + l15) * DH + 32 * ks + 8 * g];
    }

    f32x4 O[2][8];   // rows 16m+4g+i, cols d = 16db+l15
    f32x4 Ol[2];     // row sums via ones-column MFMA
#pragma unroll
    for (int m = 0; m < 2; ++m) {
        Ol[m] = (f32x4)(0.f);
#pragma unroll
        for (int db = 0; db < 8; ++db) O[m][db] = (f32x4)(0.f);
    }

    s16x8 onesf;
    {
        const short o = (l15 == 0) ? (short)0x3F80 : (short)0;
#pragma unroll
        for (int j = 0; j < 8; ++j) onesf[j] = o;
    }

    const size_t kgbase = (size_t)bh * SEQ * DH;
    const size_t vgbase = (size_t)bh * DH * SEQ;
    char* Pw = PsB + w * 8192;

    const int kt0 = split * 16;
    for (int kt = kt0; kt < kt0 + 16; ++kt) {
        __syncthreads();  // prior tile's fragment reads complete
        // stage K tile + V^T tile (32KB each): 2048 16B-slots / 512 thr
#pragma unroll
        for (int it = 0; it < 4; ++it) {
            const int slot = it * 512 + t;
            const int r    = slot >> 4;
            const int cs   = slot & 15;
            const int c    = cs ^ (r & 15);
            char* lK = KsB + (size_t)(it * 512 + 64 * w) * 16;  // wave-uniform
            gl2lds16(Kb + kgbase + (size_t)(kt * 128 + r) * DH + c * 8, lK);
            char* lV = VsB + (size_t)(it * 512 + 64 * w) * 16;
            gl2lds16(Vt + vgbase + (size_t)r * SEQ + kt * 128 + c * 8, lV);
        }
        __syncthreads();

        // S = Q K^T : rows 16m+4g+i, cols 16nb+l15; kf shared across m
        f32x4 sAcc[2][8];
#pragma unroll
        for (int m = 0; m < 2; ++m)
#pragma unroll
            for (int nb = 0; nb < 8; ++nb) sAcc[m][nb] = (f32x4)(0.f);

#pragma unroll
        for (int ks = 0; ks < 4; ++ks) {
#pragma unroll
            for (int nb = 0; nb < 8; ++nb) {
                const int n  = 16 * nb + l15;
                const int ch = (ks * 4 + g) ^ l15;
                s16x8 kf = *(const s16x8*)(KsB + n * 256 + ch * 16);
                sAcc[0][nb] = __builtin_amdgcn_mfma_f32_16x16x32_bf16(qf[0][ks], kf, sAcc[0][nb], 0, 0, 0);
                sAcc[1][nb] = __builtin_amdgcn_mfma_f32_16x16x32_bf16(qf[1][ks], kf, sAcc[1][nb], 0, 0, 0);
            }
        }

        // P = exp(S) (static max), bf16, per-wave swizzled LDS
#pragma unroll
        for (int m = 0; m < 2; ++m)
#pragma unroll
            for (int nb = 0; nb < 8; ++nb)
#pragma unroll
                for (int i = 0; i < 4; ++i) {
                    const float p  = __expf(sAcc[m][nb][i]);
                    const int row  = 16 * m + 4 * g + i;
                    const int col  = 16 * nb + l15;
                    const int e    = row * 128 + (col ^ ((row & 7) << 3));
                    *(ushort*)(Pw + e * 2) = f2bf(p);
                }

        // O += P V, l += P.ones ; vf shared across m
#pragma unroll
        for (int ks = 0; ks < 4; ++ks) {
            s16x8 pa[2];
#pragma unroll
            for (int m = 0; m < 2; ++m) {
                const int row = 16 * m + l15;
                const int e   = row * 128 + ((ks * 32 + 8 * g) ^ ((row & 7) << 3));
                pa[m] = *(const s16x8*)(Pw + e * 2);
            }
            Ol[0] = __builtin_amdgcn_mfma_f32_16x16x32_bf16(pa[0], onesf, Ol[0], 0, 0, 0);
            Ol[1] = __builtin_amdgcn_mfma_f32_16x16x32_bf16(pa[1], onesf, Ol[1], 0, 0, 0);
#pragma unroll
            for (int db = 0; db < 8; ++db) {
                const int d  = 16 * db + l15;
                const int ch = (ks * 4 + g) ^ l15;
                s16x8 vf = *(const s16x8*)(VsB + d * 256 + ch * 16);
                O[0][db] = __builtin_amdgcn_mfma_f32_16x16x32_bf16(pa[0], vf, O[0][db], 0, 0, 0);
                O[1][db] = __builtin_amdgcn_mfma_f32_16x16x32_bf16(pa[1], vf, O[1][db], 0, 0, 0);
            }
        }
    }

    // epilogue: UNNORMALIZED partial O + partial l to workspace
    float* obase = Opart + ((size_t)(split * 8 + bh) * SEQ + q0 + 32 * w) * DH;
#pragma unroll
    for (int m = 0; m < 2; ++m)
#pragma unroll
        for (int i = 0; i < 4; ++i) {
            const int r = 16 * m + 4 * g + i;   // row within wave's 32
            float* dst = obase + (size_t)r * DH;
#pragma unroll
            for (int db = 0; db < 8; ++db)
                dst[16 * db + l15] = O[m][db][i];
        }
    if (l15 == 0) {
        float* lbase = lpart + (size_t)(split * 8 + bh) * SEQ + q0 + 32 * w;
#pragma unroll
        for (int m = 0; m < 2; ++m)
#pragma unroll
            for (int i = 0; i < 4; ++i)
                lbase[16 * m + 4 * g + i] = Ol[m][i];
    }
}

// ---------------------------------------------------------------------------
// Combine: out = (O0 + O1) / (l0 + l1). 8 floats/thread, HBM-bound.
// ---------------------------------------------------------------------------
__global__ __launch_bounds__(256) void attn_combine(
    const float* __restrict__ Opart, const float* __restrict__ lpart,
    float* __restrict__ out)
{
    const int f = blockIdx.x * 256 + threadIdx.x;  // 0..524287
    const int c = f & 63;            // chunk of 8 within (b,n): h=c>>4, d=(c&15)*8
    const int n = (f >> 6) & 4095;
    const int b = f >> 18;
    const int h = c >> 4;
    const int d = (c & 15) * 8;
    const int bh = b * NH + h;

    const size_t o0 = ((size_t)bh * SEQ + n) * DH + d;
    const size_t o1 = ((size_t)(8 + bh) * SEQ + n) * DH + d;
    float4 a0 = *(const float4*)&Opart[o0];
    float4 a1 = *(const float4*)&Opart[o0 + 4];
    float4 b0 = *(const float4*)&Opart[o1];
    float4 b1 = *(const float4*)&Opart[o1 + 4];
    const float inv = 1.f / (lpart[(size_t)bh * SEQ + n] + lpart[(size_t)(8 + bh) * SEQ + n]);

    float4 r0, r1;
    r0.x = (a0.x + b0.x) * inv; r0.y = (a0.y + b0.y) * inv;
    r0.z = (a0.z + b0.z) * inv; r0.w = (a0.w + b0.w) * inv;
    r1.x = (a1.x + b1.x) * inv; r1.y = (a1.y + b1.y) * inv;
    r1.z = (a1.z + b1.z) * inv; r1.w = (a1.w + b1.w) * inv;

    float* dst = out + ((size_t)b * SEQ + n) * DMODEL + h * DH + d;
    *(float4*)&dst[0] = r0;
    *(float4*)&dst[4] = r1;
}

// ---------------------------------------------------------------------------
extern "C" void kernel_launch(void* const* d_in, const int* in_sizes, int n_in,
                              void* d_out, int out_size, void* d_ws, size_t ws_size,
                              hipStream_t stream) {
    const float* x    = (const float*)d_in[0];  // [2,4096,512]
    const float* W    = (const float*)d_in[1];  // [1536,512]
    const float* bias = (const float*)d_in[2];  // [1536]
    float* outp = (float*)d_out;                // [2,4096,512]

    ushort* xb = (ushort*)d_ws;                       // [8192][512] bf16
    ushort* Wb = xb + (size_t)2 * SEQ * DMODEL;       // [1536][512] bf16
    ushort* Qb = Wb + (size_t)3 * NH * DH * DMODEL;   // [8][4096][128] bf16
    ushort* Kb = Qb + (size_t)2 * NH * SEQ * DH;
    ushort* Vt = Kb + (size_t)2 * NH * SEQ * DH;      // [8][128][4096] bf16
    float* Opart = (float*)(Vt + (size_t)2 * NH * SEQ * DH);  // [2][8][4096][128] f32
    float* lpart = Opart + (size_t)2 * 2 * NH * SEQ * DH;     // [2][8][4096] f32

    hipFuncSetAttribute((const void*)flash_attn_mfma,
                        hipFuncAttributeMaxDynamicSharedMemorySize, 131072);

    cast_bf16<<<2048, 256, 0, stream>>>(x, xb);
    cast_bf16<<<384, 256, 0, stream>>>(W, Wb);
    qkv_gemm<<<dim3(12, 64), 256, 0, stream>>>(xb, Wb, bias, Qb, Kb, Vt);
    flash_attn_mfma<<<dim3(16, 16), 512, 131072, stream>>>(Qb, Kb, Vt, Opart, lpart);
    attn_combine<<<2048, 256, 0, stream>>>(Opart, lpart, outp);
}